// Round 25
// baseline (538.015 us; speedup 1.0000x reference)
//
#include <hip/hip_runtime.h>
#include <math.h>

#define ATT0_BLOCKS 1024

typedef __attribute__((ext_vector_type(8))) short short8_t;
typedef __attribute__((ext_vector_type(4))) float f32x4;

// branch-free GELU: gelu(x) = 0.5x + 0.5x*erf(x/sqrt2), erf via A&S 7.1.26
__device__ __forceinline__ float gelu_f(float x) {
    float ax = fabsf(x) * 0.70710678118654752f;
    float t = __builtin_amdgcn_rcpf(fmaf(ax, 0.3275911f, 1.0f));
    float p = fmaf(t, 1.061405429f, -1.453152027f);
    p = fmaf(t, p, 1.421413741f);
    p = fmaf(t, p, -0.284496736f);
    p = fmaf(t, p, 0.254829592f);
    p = p * t;
    float e = __expf(-ax * ax);
    float erfv = 1.0f - p * e;          // erf(|x|/sqrt2) >= 0
    return fmaf(0.5f * copysignf(erfv, x), x, 0.5f * x);
}

__device__ __forceinline__ float pe_val(int pos, int j, int D) {
    int i2 = j & ~1;
    float freq = expf(-9.210340371976184f * (float)i2 / (float)D); // -ln(10000)
    float arg = (float)pos * freq;
    return (j & 1) ? cosf(arg) : sinf(arg);
}

__device__ __forceinline__ unsigned short f2bf(float f) {
    unsigned u = __float_as_uint(f);
    return (unsigned short)((u + 0x7fffu + ((u >> 16) & 1u)) >> 16);
}
__device__ __forceinline__ float bf2f(unsigned short u) {
    return __uint_as_float(((unsigned)u) << 16);
}

// swizzled bf16 LDS tile: rows of 256 bf16 (512 B), byte ^= (row&7)<<4
__device__ __forceinline__ void st_bf(unsigned short* X2, int row, int col, unsigned short v) {
    int byte = (row * 512 + col * 2) ^ ((row & 7) << 4);
    *(unsigned short*)((char*)X2 + byte) = v;
}
__device__ __forceinline__ short8_t ldA(const unsigned short* X2, int m, int ks, int l) {
    int byte = (m * 512 + ks * 64 + ((l >> 4) << 4)) ^ ((m & 7) << 4);
    return *(const short8_t*)((const char*)X2 + byte);
}

// ---------------------------------------------------------------------------
// K0: pack ALL eight fp32 weights into fragment-linear bf16 in one launch.
// ---------------------------------------------------------------------------
__global__ __launch_bounds__(256) void k_pack_all(
    const float* __restrict__ s_m1W1, const float* __restrict__ s_m1W2,
    const float* __restrict__ s_kW,   const float* __restrict__ s_vW,
    const float* __restrict__ s_m2W1, const float* __restrict__ s_m2W2,
    const float* __restrict__ s_m3W1, const float* __restrict__ s_m3W2,
    unsigned short* __restrict__ pk)
{
    int b = blockIdx.x, tid = threadIdx.x;
    const float* src; int CT, ld, base; size_t dstOff;
    if (b < 256)       { src = s_m1W1; CT = 16; ld = 256; base = 0;    dstOff = 0; }
    else if (b < 512)  { src = s_m1W2; CT = 16; ld = 256; base = 256;  dstOff = 65536; }
    else if (b < 1024) { src = s_kW;   CT = 32; ld = 512; base = 512;  dstOff = 131072; }
    else if (b < 1280) { src = s_vW;   CT = 16; ld = 256; base = 1024; dstOff = 262144; }
    else if (b < 1536) { src = s_m2W1; CT = 16; ld = 256; base = 1280; dstOff = 327680; }
    else if (b < 1792) { src = s_m2W2; CT = 16; ld = 256; base = 1536; dstOff = 393216; }
    else if (b < 2048) { src = s_m3W1; CT = 16; ld = 256; base = 1792; dstOff = 458752; }
    else               { src = s_m3W2; CT = 16; ld = 256; base = 2048; dstOff = 524288; }
    int idx = (b - base) * 256 + tid;
    if (idx >= 4096 * CT) return;
    int i = idx & 7, l = (idx >> 3) & 63, fc = idx >> 9;
    int c = fc % CT, ks = fc / CT;
    int k = ks * 32 + ((l >> 4) << 3) + i;
    int col = c * 16 + (l & 15);
    pk[dstOff + idx] = f2bf(src[(size_t)k * ld + col]);
}

// ---------------------------------------------------------------------------
// MFMA stage, 2 row-tiles (32 rows) x NT col-tiles, setprio around MFMA loop
// ---------------------------------------------------------------------------
template <int NT>
__device__ __forceinline__ void mm_frag(const unsigned short* X2,
                                        const unsigned short* __restrict__ Wp,
                                        int CT, int ct0, int l, f32x4 acc[2][NT])
{
    #pragma unroll
    for (int rt = 0; rt < 2; ++rt)
        #pragma unroll
        for (int t = 0; t < NT; ++t)
            acc[rt][t] = (f32x4){0.f, 0.f, 0.f, 0.f};
    __builtin_amdgcn_s_setprio(1);
    #pragma unroll
    for (int ks = 0; ks < 8; ++ks) {
        short8_t a0 = ldA(X2, (l & 15), ks, l);
        short8_t a1 = ldA(X2, 16 + (l & 15), ks, l);
        #pragma unroll
        for (int t = 0; t < NT; ++t) {
            short8_t b = *(const short8_t*)(Wp + (size_t)((ks * CT + ct0 + t) * 64 + l) * 8);
            acc[0][t] = __builtin_amdgcn_mfma_f32_16x16x32_bf16(a0, b, acc[0][t], 0, 0, 0);
            acc[1][t] = __builtin_amdgcn_mfma_f32_16x16x32_bf16(a1, b, acc[1][t], 0, 0, 0);
        }
    }
    __builtin_amdgcn_s_setprio(0);
}

// ---------------------------------------------------------------------------
// Barrier-free LN over bf16 [32][272] with 256 threads: 8 lanes/row
// ---------------------------------------------------------------------------
__device__ __forceinline__ void ln32h_nb256(const unsigned short* Ah, unsigned short* X2,
                                            const float* __restrict__ g,
                                            const float* __restrict__ bvec, int tid)
{
    int l = tid & 7, row = tid >> 3;      // 32 rows x 8 lanes
    float s = 0.f, q = 0.f;
    #pragma unroll
    for (int i = 0; i < 32; ++i) {
        float v = bf2f(Ah[row * 272 + l + i * 8]); s += v; q += v * v;
    }
    #pragma unroll
    for (int off = 1; off < 8; off <<= 1) {
        s += __shfl_xor(s, off); q += __shfl_xor(q, off);
    }
    float mean = s * (1.f / 256.f);
    float rstd = rsqrtf(q * (1.f / 256.f) - mean * mean + 1e-5f);
    #pragma unroll
    for (int i = 0; i < 32; ++i) {
        int col = l + i * 8;
        float v = (bf2f(Ah[row * 272 + col]) - mean) * rstd * g[col] + bvec[col];
        st_bf(X2, row, col, f2bf(v));
    }
}

// ---------------------------------------------------------------------------
// Barrier-free LN over bf16 [32][272] with 512 threads: 16 lanes/row.
// Row-slice cached in registers: single LDS read pass.
// ---------------------------------------------------------------------------
__device__ __forceinline__ void ln32h_nb512(const unsigned short* Ah, unsigned short* X2,
                                            const float* __restrict__ g,
                                            const float* __restrict__ bvec, int tid)
{
    int l = tid & 15, row = tid >> 4;     // 32 rows x 16 lanes
    float lv[16];
    float s = 0.f, q = 0.f;
    #pragma unroll
    for (int i = 0; i < 16; ++i) {
        float v = bf2f(Ah[row * 272 + l + i * 16]);
        lv[i] = v;
        s += v; q += v * v;
    }
    #pragma unroll
    for (int off = 1; off < 16; off <<= 1) {
        s += __shfl_xor(s, off); q += __shfl_xor(q, off);
    }
    float mean = s * (1.f / 256.f);
    float rstd = rsqrtf(q * (1.f / 256.f) - mean * mean + 1e-5f);
    #pragma unroll
    for (int i = 0; i < 16; ++i) {
        int col = l + i * 16;
        float v = (lv[i] - mean) * rstd * g[col] + bvec[col];
        st_bf(X2, row, col, f2bf(v));
    }
}

// ---------------------------------------------------------------------------
// K1: tiny setup — q rows, bias rows, c2/c3 constant vectors
// ---------------------------------------------------------------------------
__global__ __launch_bounds__(256) void k_small(
    const float* __restrict__ qW1, const float* __restrict__ qb1,
    const float* __restrict__ qW2, const float* __restrict__ qb2,
    const float* __restrict__ bW1, const float* __restrict__ bb1,
    const float* __restrict__ bW2, const float* __restrict__ bb2,
    const float* __restrict__ m2W1, const float* __restrict__ m2b1,
    const float* __restrict__ m3W1, const float* __restrict__ m3b1,
    float* __restrict__ q01, float* __restrict__ ball,
    float* __restrict__ c2, float* __restrict__ c3)
{
    __shared__ float pe[256];
    __shared__ float h[256];
    int b = blockIdx.x, tid = threadIdx.x;
    if (b < 11) {
        int pos = (b < 2) ? b : (b - 2);
        if (tid < 64) pe[tid] = pe_val(pos, tid, 64);
        __syncthreads();
        const float* W1 = (b < 2) ? qW1 : bW1;
        const float* b1 = (b < 2) ? qb1 : bb1;
        const float* W2 = (b < 2) ? qW2 : bW2;
        const float* b2 = (b < 2) ? qb2 : bb2;
        float acc = b1[tid];
        for (int d = 0; d < 64; ++d) acc += pe[d] * W1[d * 256 + tid];
        h[tid] = gelu_f(acc);
        __syncthreads();
        float acc2 = b2[tid];
        for (int d = 0; d < 256; ++d) acc2 += h[d] * W2[d * 256 + tid];
        if (b < 2) q01[b * 256 + tid] = acc2;
        else ball[(b - 2) * 256 + tid] = acc2;
    } else {
        int pos; const float* W1; const float* b1; float* dst;
        if (b < 13) { pos = b - 11; W1 = m2W1; b1 = m2b1; dst = c2 + pos * 256; }
        else        { pos = b - 13; W1 = m3W1; b1 = m3b1; dst = c3 + pos * 256; }
        pe[tid] = pe_val(pos, tid, 256);
        __syncthreads();
        float acc = b1[tid];
        for (int d = 0; d < 256; ++d) acc += pe[d] * W1[(256 + d) * 256 + tid];
        dst[tid] = acc;
    }
}

// ---------------------------------------------------------------------------
// K2 (32-row, bf16 Ah + X2 dbuf, 4 barriers): x1 = x + mlp1(ln(x));
// v -> vbf (VB) or fp32; logits from kW accumulators
// ---------------------------------------------------------------------------
template <bool VB>
__global__ __launch_bounds__(256) void k_node(
    const float* __restrict__ x,
    const unsigned short* __restrict__ m1W1p, const float* __restrict__ m1b1,
    const unsigned short* __restrict__ m1W2p, const float* __restrict__ m1b2,
    const float* __restrict__ n1g, const float* __restrict__ n1b,
    const unsigned short* __restrict__ kWp, const float* __restrict__ kb,
    const unsigned short* __restrict__ vWp, const float* __restrict__ vb,
    const float* __restrict__ q01,
    float* __restrict__ v_out, unsigned short* __restrict__ vbf,
    float* __restrict__ lg0, float* __restrict__ lg1, int N)
{
    __shared__ __align__(16) unsigned short Ah[32 * 272];    // 17408 B
    __shared__ __align__(16) unsigned short X2a[32 * 256];   // 16384 B
    __shared__ __align__(16) unsigned short X2b[32 * 256];   // 16384 B

    int tid = threadIdx.x;
    int l = tid & 63, wid = tid >> 6, l15 = l & 15;
    int row0 = blockIdx.x * 32;

    {
        #pragma unroll
        for (int it = 0; it < 8; ++it) {
            int slot = it * 256 + tid;          // 2048 slots x 4 floats
            int row = slot >> 6, c0 = (slot & 63) * 4;
            int n = row0 + row;
            float4 f = (n < N) ? *(const float4*)(x + (size_t)n * 256 + c0)
                               : (float4){0.f, 0.f, 0.f, 0.f};
            ushort4 hv = {f2bf(f.x), f2bf(f.y), f2bf(f.z), f2bf(f.w)};
            *(ushort4*)&Ah[row * 272 + c0] = hv;
        }
    }
    __syncthreads();                               // B1: Ah visible
    ln32h_nb256(Ah, X2a, n1g, n1b, tid);
    __syncthreads();                               // B2: X2a (LN) visible

    f32x4 acc[2][4];
    // mlp1 stage 1: read X2a, write h -> X2b
    mm_frag<4>(X2a, m1W1p, 16, wid * 4, l, acc);
    #pragma unroll
    for (int rt = 0; rt < 2; ++rt)
        #pragma unroll
        for (int t = 0; t < 4; ++t) {
            int col = (wid * 4 + t) * 16 + l15;
            float bb = m1b1[col];
            #pragma unroll
            for (int r = 0; r < 4; ++r) {
                int row = rt * 16 + ((l >> 4) << 2) + r;
                st_bf(X2b, row, col, f2bf(gelu_f(acc[rt][t][r] + bb)));
            }
        }
    __syncthreads();                               // B3: h (X2b) visible
    // mlp1 stage 2: read X2b, x1 = Ah + acc + b -> X2a
    mm_frag<4>(X2b, m1W2p, 16, wid * 4, l, acc);
    #pragma unroll
    for (int rt = 0; rt < 2; ++rt)
        #pragma unroll
        for (int t = 0; t < 4; ++t) {
            int col = (wid * 4 + t) * 16 + l15;
            float bb = m1b2[col];
            #pragma unroll
            for (int r = 0; r < 4; ++r) {
                int row = rt * 16 + ((l >> 4) << 2) + r;
                float nv = bf2f(Ah[row * 272 + col]) + acc[rt][t][r] + bb;
                st_bf(X2a, row, col, f2bf(nv));
            }
        }
    __syncthreads();                               // B4: x1 (X2a) visible

    {
        f32x4 acck[2][8];
        mm_frag<8>(X2a, kWp, 32, wid * 8, l, acck);
        int which = wid >> 1;
        int h0 = (wid & 1) * 4;
        float lp[2][4][4];
        #pragma unroll
        for (int rt = 0; rt < 2; ++rt)
            #pragma unroll
            for (int r = 0; r < 4; ++r)
                #pragma unroll
                for (int hl = 0; hl < 4; ++hl) lp[rt][r][hl] = 0.f;
        #pragma unroll
        for (int t = 0; t < 8; ++t) {
            int d = ((t & 1) << 4) | l15;
            int h = h0 + (t >> 1);
            int col = (which * 16 + (wid & 1) * 8 + t) * 16 + l15;
            float qv = q01[which * 256 + h * 32 + d];
            float kbv = kb[col];
            #pragma unroll
            for (int rt = 0; rt < 2; ++rt)
                #pragma unroll
                for (int r = 0; r < 4; ++r)
                    lp[rt][r][t >> 1] += qv * (acck[rt][t][r] + kbv);
        }
        #pragma unroll
        for (int off = 1; off < 16; off <<= 1)
            #pragma unroll
            for (int rt = 0; rt < 2; ++rt)
                #pragma unroll
                for (int r = 0; r < 4; ++r)
                    #pragma unroll
                    for (int hl = 0; hl < 4; ++hl)
                        lp[rt][r][hl] += __shfl_xor(lp[rt][r][hl], off);
        if (l15 == 0) {
            float* dst = which ? lg1 : lg0;
            #pragma unroll
            for (int rt = 0; rt < 2; ++rt)
                #pragma unroll
                for (int r = 0; r < 4; ++r) {
                    int n = row0 + rt * 16 + ((l >> 4) << 2) + r;
                    if (n < N)
                        #pragma unroll
                        for (int hl = 0; hl < 4; ++hl)
                            dst[(size_t)n * 8 + h0 + hl] = lp[rt][r][hl] * 0.17677669529663687f;
                }
        }
    }
    mm_frag<4>(X2a, vWp, 16, wid * 4, l, acc);
    #pragma unroll
    for (int rt = 0; rt < 2; ++rt)
        #pragma unroll
        for (int t = 0; t < 4; ++t) {
            int col = (wid * 4 + t) * 16 + l15;
            float bb = vb[col];
            #pragma unroll
            for (int r = 0; r < 4; ++r) {
                int n = row0 + rt * 16 + ((l >> 4) << 2) + r;
                if (n < N) {
                    float val = acc[rt][t][r] + bb;
                    if (VB) vbf[(size_t)n * 256 + col] = f2bf(val);
                    else    v_out[(size_t)n * 256 + col] = val;
                }
            }
        }
}

// ---------------------------------------------------------------------------
// K3 (merged): blocks [0,g1) = att1e gather; [g1,g1+ATT0_BLOCKS) = att0 partials
// ---------------------------------------------------------------------------
template <bool OBF>
__global__ __launch_bounds__(256) void k_gath0(
    const int* __restrict__ node_idx, const float* __restrict__ lg1,
    const float* __restrict__ lg0, const unsigned short* __restrict__ vbf,
    void* __restrict__ outp, float* __restrict__ part, int N, int E, int g1)
{
    __shared__ int nidS[32];
    int tid = threadIdx.x;
    if ((int)blockIdx.x < g1) {
        int wid = tid >> 6, l = tid & 63;
        int e = blockIdx.x * 4 + wid;
        bool alive = e < E;
        if (l < 8) nidS[wid * 8 + l] = alive ? node_idx[(size_t)e * 8 + l] : 0;
        __syncthreads();
        float lgv = lg1[(size_t)nidS[wid * 8 + (l >> 3)] * 8 + (l & 7)];
        float m = lgv;
        m = fmaxf(m, __shfl_xor(m, 8));
        m = fmaxf(m, __shfl_xor(m, 16));
        m = fmaxf(m, __shfl_xor(m, 32));
        float w = __expf(lgv - m);
        float den = w;
        den += __shfl_xor(den, 8);
        den += __shfl_xor(den, 16);
        den += __shfl_xor(den, 32);
        float wn = w / den;
        int c0 = l * 4, myh = l >> 3;
        float a0 = 0.f, a1 = 0.f, a2 = 0.f, a3 = 0.f;
        #pragma unroll
        for (int i = 0; i < 8; ++i) {
            float ws = __shfl(wn, i * 8 + myh);
            int ni = nidS[wid * 8 + i];
            ushort4 pv = *(const ushort4*)(vbf + (size_t)ni * 256 + c0);
            a0 = fmaf(ws, bf2f(pv.x), a0);
            a1 = fmaf(ws, bf2f(pv.y), a1);
            a2 = fmaf(ws, bf2f(pv.z), a2);
            a3 = fmaf(ws, bf2f(pv.w), a3);
        }
        if (alive) {
            if (OBF) {
                ushort4 o = {f2bf(a0), f2bf(a1), f2bf(a2), f2bf(a3)};
                *(ushort4*)((unsigned short*)outp + (size_t)e * 256 + c0) = o;
            } else {
                float4 o = {a0, a1, a2, a3};
                *(float4*)((float*)outp + (size_t)e * 256 + c0) = o;
            }
        }
    } else {
        int b = (int)blockIdx.x - g1;
        int chunk = (N + ATT0_BLOCKS - 1) / ATT0_BLOCKS;
        int n0 = b * chunk, n1 = min(N, n0 + chunk);
        int h = tid >> 5;
        float acc = 0.f, dacc = 0.f;
        for (int n = n0; n < n1; ++n) {
            float e = __expf(lg0[(size_t)n * 8 + h]);
            float vv = bf2f(vbf[(size_t)n * 256 + tid]);
            acc += e * vv;
            if ((tid & 31) == 0) dacc += e;
        }
        part[b * 264 + tid] = acc;
        if ((tid & 31) == 0) part[b * 264 + 256 + h] = dacc;
    }
}

// fp32 fallback variants
template <bool BF>
__global__ __launch_bounds__(256) void k_att0_partial(
    const float* __restrict__ lg0, const float* __restrict__ v,
    const unsigned short* __restrict__ vbf, int N, float* __restrict__ part)
{
    int tid = threadIdx.x, b = blockIdx.x;
    int chunk = (N + ATT0_BLOCKS - 1) / ATT0_BLOCKS;
    int n0 = b * chunk, n1 = min(N, n0 + chunk);
    int h = tid >> 5;
    float acc = 0.f, dacc = 0.f;
    for (int n = n0; n < n1; ++n) {
        float e = __expf(lg0[(size_t)n * 8 + h]);
        float vv = BF ? bf2f(vbf[(size_t)n * 256 + tid]) : v[(size_t)n * 256 + tid];
        acc += e * vv;
        if ((tid & 31) == 0) dacc += e;
    }
    part[b * 264 + tid] = acc;
    if ((tid & 31) == 0) part[b * 264 + 256 + h] = dacc;
}

__global__ __launch_bounds__(256) void k_att0_final(
    const float* __restrict__ part,
    const float* __restrict__ m2W1, const float* __restrict__ m2W2,
    const float* __restrict__ m2b2,
    const float* __restrict__ n2g, const float* __restrict__ n2b,
    const float* __restrict__ c2, float* __restrict__ att0f)
{
    __shared__ float L[256], H[256], red[16], dsh[8];
    int tid = threadIdx.x;
    float s = 0.f;
    for (int b = 0; b < ATT0_BLOCKS; ++b) s += part[b * 264 + tid];
    if (tid < 8) {
        float d = 0.f;
        for (int b = 0; b < ATT0_BLOCKS; ++b) d += part[b * 264 + 256 + tid];
        dsh[tid] = d;
    }
    __syncthreads();
    float a = s / dsh[tid >> 5];
    float ss = a, sq = a * a;
    for (int off = 32; off; off >>= 1) { ss += __shfl_down(ss, off); sq += __shfl_down(sq, off); }
    int lane = tid & 63, wid = tid >> 6;
    if (lane == 0) { red[wid] = ss; red[4 + wid] = sq; }
    __syncthreads();
    if (tid == 0) {
        float S1 = red[0] + red[1] + red[2] + red[3];
        float S2 = red[4] + red[5] + red[6] + red[7];
        float mean = S1 / 256.f, var = S2 / 256.f - mean * mean;
        red[8] = mean; red[9] = rsqrtf(var + 1e-5f);
    }
    __syncthreads();
    L[tid] = (a - red[8]) * red[9] * n2g[tid] + n2b[tid];
    __syncthreads();
    float acc = c2[tid];
    for (int d = 0; d < 256; ++d) acc += L[d] * m2W1[d * 256 + tid];
    H[tid] = gelu_f(acc);
    __syncthreads();
    float acc2 = m2b2[tid];
    for (int d = 0; d < 256; ++d) acc2 += H[d] * m2W2[d * 256 + tid];
    att0f[tid] = a + acc2;
}

// fp32 fallback (block-per-edge)
__global__ __launch_bounds__(256) void k_att1e(
    const int* __restrict__ node_idx, const float* __restrict__ lg1,
    const float* __restrict__ v, float* __restrict__ oute)
{
    __shared__ int nid[8];
    __shared__ float lgS[64];
    int e = blockIdx.x, tid = threadIdx.x;
    if (tid < 8) nid[tid] = node_idx[e * 8 + tid];
    __syncthreads();
    if (tid < 64) { int i = tid >> 3, h = tid & 7; lgS[i * 8 + h] = lg1[(size_t)nid[i] * 8 + h]; }
    __syncthreads();
    int h = tid >> 5;
    float m = -1e30f;
    #pragma unroll
    for (int i = 0; i < 8; ++i) m = fmaxf(m, lgS[i * 8 + h]);
    float w[8], den = 0.f;
    #pragma unroll
    for (int i = 0; i < 8; ++i) { w[i] = __expf(lgS[i * 8 + h] - m); den += w[i]; }
    float acc = 0.f;
    #pragma unroll
    for (int i = 0; i < 8; ++i) acc += w[i] * v[(size_t)nid[i] * 256 + tid];
    oute[(size_t)e * 256 + tid] = acc / den;
}

// ---------------------------------------------------------------------------
// K5 (512 threads, 32 rows, acc[2][2] col-pair waves, residual register-carry):
// blk2+att0+blk3+bias, 6 barriers per 32 rows. [0,nb0)=node; [nb0,..)=edge.
// ---------------------------------------------------------------------------
__global__ __launch_bounds__(512) void k_blk23(
    const void* __restrict__ in_v, int node_bf, float* __restrict__ out_v, int Mn, int nb0,
    const void* __restrict__ in_e, int edge_bf, float* __restrict__ out_e, int Me,
    const unsigned short* __restrict__ m2W1p, const unsigned short* __restrict__ m2W2p,
    const float* __restrict__ m2b2,
    const unsigned short* __restrict__ m3W1p, const unsigned short* __restrict__ m3W2p,
    const float* __restrict__ m3b2,
    const float* __restrict__ n2g, const float* __restrict__ n2b,
    const float* __restrict__ n3g, const float* __restrict__ n3b,
    const float* __restrict__ c2row, const float* __restrict__ c3tab,
    const float* __restrict__ att0f, const float* __restrict__ ball,
    const int* __restrict__ orders)
{
    __shared__ __align__(16) unsigned short Ah[32 * 272];    // 17408 B
    __shared__ __align__(16) unsigned short X2a[32 * 256];   // 16384 B
    __shared__ __align__(16) unsigned short X2b[32 * 256];   // 16384 B
    __shared__ int ords[32];

    int tid = threadIdx.x;
    int l = tid & 63, wid = tid >> 6, l15 = l & 15, gq = l >> 4;
    bool edge = (int)blockIdx.x >= nb0;
    int row0 = (edge ? (int)blockIdx.x - nb0 : (int)blockIdx.x) * 32;
    int M = edge ? Me : Mn;
    float* outp = edge ? out_e : out_v;
    int inbf = edge ? edge_bf : node_bf;
    const void* inp = edge ? in_e : in_v;

    if (inbf) {
        const unsigned short* inH = (const unsigned short*)inp;
        #pragma unroll
        for (int it = 0; it < 4; ++it) {
            int slot = it * 512 + tid;          // 2048 slots x 4 bf16
            int row = slot >> 6, c0 = (slot & 63) * 4;
            int n = row0 + row;
            ushort4 hv = (n < M) ? *(const ushort4*)(inH + (size_t)n * 256 + c0)
                                 : (ushort4){0, 0, 0, 0};
            *(ushort4*)&Ah[row * 272 + c0] = hv;
        }
    } else {
        const float* inF = (const float*)inp;
        #pragma unroll
        for (int it = 0; it < 4; ++it) {
            int slot = it * 512 + tid;
            int row = slot >> 6, c0 = (slot & 63) * 4;
            int n = row0 + row;
            float4 f = (n < M) ? *(const float4*)(inF + (size_t)n * 256 + c0)
                               : (float4){0.f, 0.f, 0.f, 0.f};
            ushort4 hv = {f2bf(f.x), f2bf(f.y), f2bf(f.z), f2bf(f.w)};
            *(ushort4*)&Ah[row * 272 + c0] = hv;
        }
    }
    if (tid < 32) {
        int n = row0 + tid;
        ords[tid] = (edge && n < M) ? orders[n] : 1;
    }
    __syncthreads();                               // B1: Ah + ords visible

    f32x4 acc[2][2];
    float resv[2][2][4];                           // residual register-carry
    // ---- blk2 ----
    ln32h_nb512(Ah, X2a, n2g, n2b, tid);
    __syncthreads();                               // B2: X2a (LN) visible
    mm_frag<2>(X2a, m2W1p, 16, wid * 2, l, acc);
    #pragma unroll
    for (int rt = 0; rt < 2; ++rt)
        #pragma unroll
        for (int t = 0; t < 2; ++t) {
            int col = (wid * 2 + t) * 16 + l15;
            float bb = c2row[col];
            #pragma unroll
            for (int r = 0; r < 4; ++r)
                st_bf(X2b, rt * 16 + gq * 4 + r, col, f2bf(gelu_f(acc[rt][t][r] + bb)));
        }
    __syncthreads();                               // B3: h (X2b) visible
    mm_frag<2>(X2b, m2W2p, 16, wid * 2, l, acc);
    #pragma unroll
    for (int rt = 0; rt < 2; ++rt)
        #pragma unroll
        for (int t = 0; t < 2; ++t) {
            int col = (wid * 2 + t) * 16 + l15;
            float bb = m2b2[col] + att0f[col];
            #pragma unroll
            for (int r = 0; r < 4; ++r) {
                int row = rt * 16 + gq * 4 + r;
                float nv = bf2f(Ah[row * 272 + col]) + acc[rt][t][r] + bb;
                unsigned short hv = f2bf(nv);
                Ah[row * 272 + col] = hv;
                resv[rt][t][r] = bf2f(hv);         // exact value epilogue would re-read
            }
        }
    __syncthreads();                               // B4: Ah updated
    // ---- blk3 ----
    ln32h_nb512(Ah, X2a, n3g, n3b, tid);
    __syncthreads();                               // B5: X2a visible
    mm_frag<2>(X2a, m3W1p, 16, wid * 2, l, acc);
    #pragma unroll
    for (int rt = 0; rt < 2; ++rt)
        #pragma unroll
        for (int t = 0; t < 2; ++t) {
            int col = (wid * 2 + t) * 16 + l15;
            #pragma unroll
            for (int r = 0; r < 4; ++r) {
                int row = rt * 16 + gq * 4 + r;
                float bb = c3tab[ords[row] * 256 + col];
                st_bf(X2b, row, col, f2bf(gelu_f(acc[rt][t][r] + bb)));
            }
        }
    __syncthreads();                               // B6: h (X2b) visible
    mm_frag<2>(X2b, m3W2p, 16, wid * 2, l, acc);
    #pragma unroll
    for (int rt = 0; rt < 2; ++rt)
        #pragma unroll
        for (int t = 0; t < 2; ++t) {
            int col = (wid * 2 + t) * 16 + l15;
            float bb = m3b2[col];
            #pragma unroll
            for (int r = 0; r < 4; ++r) {
                int row = rt * 16 + gq * 4 + r;
                int n = row0 + row;
                if (n < M)
                    outp[(size_t)n * 256 + col] =
                        resv[rt][t][r] + acc[rt][t][r] + bb
                        + ball[ords[row] * 256 + col];
            }
        }
}

extern "C" void kernel_launch(void* const* d_in, const int* in_sizes, int n_in,
                              void* d_out, int out_size, void* d_ws, size_t ws_size,
                              hipStream_t stream)
{
    const float* x          = (const float*)d_in[0];
    const int*   node_idx   = (const int*)d_in[1];
    const int*   edge_orders= (const int*)d_in[3];
    const float* qW1 = (const float*)d_in[4];
    const float* qb1 = (const float*)d_in[5];
    const float* qW2 = (const float*)d_in[6];
    const float* qb2 = (const float*)d_in[7];
    const float* kW  = (const float*)d_in[8];
    const float* kb  = (const float*)d_in[9];
    const float* vW  = (const float*)d_in[10];
    const float* vb  = (const float*)d_in[11];
    const float* m1W1= (const float*)d_in[12];
    const float* m1b1= (const float*)d_in[13];
    const float* m1W2= (const float*)d_in[14];
    const float* m1b2= (const float*)d_in[15];
    const float* m2W1= (const float*)d_in[16];
    const float* m2b1= (const float*)d_in[17];
    const float* m2W2= (const float*)d_in[18];
    const float* m2b2= (const float*)d_in[19];
    const float* m3W1= (const float*)d_in[20];
    const float* m3b1= (const float*)d_in[21];
    const float* m3W2= (const float*)d_in[22];
    const float* m3b2= (const float*)d_in[23];
    const float* n1g = (const float*)d_in[24];
    const float* n1b = (const float*)d_in[25];
    const float* n2g = (const float*)d_in[26];
    const float* n2b = (const float*)d_in[27];
    const float* n3g = (const float*)d_in[28];
    const float* n3b = (const float*)d_in[29];
    const float* bW1 = (const float*)d_in[30];
    const float* bb1 = (const float*)d_in[31];
    const float* bW2 = (const float*)d_in[32];
    const float* bb2 = (const float*)d_in[33];

    int N = in_sizes[0] / 256;
    int E = in_sizes[3];

    float* ws    = (float*)d_ws;
    float* q01   = ws;               // 512
    float* ball  = ws + 512;         // 9*256
    float* c2    = ws + 2816;        // 2*256
    float* c3    = ws + 3328;        // 9*256
    float* att0f = ws + 5632;        // 256
    float* part  = ws + 5888;        // 1024*264 -> ends 276224
    float* lg0   = ws + 276224;      // N*8
    float* lg1   = lg0 + (size_t)N * 8;            // ends 276224 + 2*N*8
    unsigned short* pk = (unsigned short*)(ws + 1076224);
    unsigned short* m1W1p = pk;
    unsigned short* m1W2p = pk + 65536;
    unsigned short* kWp   = pk + 131072;
    unsigned short* vWp   = pk + 262144;
    unsigned short* m2W1p = pk + 327680;
    unsigned short* m2W2p = pk + 393216;
    unsigned short* m3W1p = pk + 458752;
    unsigned short* m3W2p = pk + 524288;   // pk ends at float offset 1371136
    unsigned short* vbf = (unsigned short*)(ws + 1371136);
    unsigned short* aeb = vbf + (size_t)N * 256;
    size_t need1 = 1371136ull * 4 + (size_t)N * 256 * 2;
    size_t need2 = need1 + (size_t)E * 256 * 2;
    bool use_bf  = (ws_size >= need1);
    bool use_ebf = (ws_size >= need2);

    float* v_out = (float*)d_out;                       // [N,256]: x_v (fallback: v then x_v)
    float* out_e = (float*)d_out + (size_t)N * 256;     // [E,256]: att1_e, then x_e

    k_pack_all<<<2304, 256, 0, stream>>>(m1W1, m1W2, kW, vW, m2W1, m2W2, m3W1, m3W2, pk);
    k_small<<<22, 256, 0, stream>>>(qW1, qb1, qW2, qb2, bW1, bb1, bW2, bb2,
                                    m2W1, m2b1, m3W1, m3b1, q01, ball, c2, c3);

    int nb0 = (N + 31) / 32, nb1 = (E + 31) / 32;
    int nnode = (N + 31) / 32;
    int g1 = (E + 3) / 4;
    if (use_bf) {
        k_node<true><<<nnode, 256, 0, stream>>>(x, m1W1p, m1b1, m1W2p, m1b2, n1g, n1b,
                                                kWp, kb, vWp, vb, q01, nullptr, vbf,
                                                lg0, lg1, N);
        if (use_ebf) {
            k_gath0<true><<<g1 + ATT0_BLOCKS, 256, 0, stream>>>(node_idx, lg1, lg0, vbf,
                                                                aeb, part, N, E, g1);
            k_att0_final<<<1, 256, 0, stream>>>(part, m2W1, m2W2, m2b2, n2g, n2b, c2, att0f);
            k_blk23<<<nb0 + nb1, 512, 0, stream>>>(vbf, 1, v_out, N, nb0, aeb, 1, out_e, E,
                m2W1p, m2W2p, m2b2, m3W1p, m3W2p, m3b2, n2g, n2b, n3g, n3b,
                c2 + 256, c3, att0f, ball, edge_orders);
        } else {
            k_gath0<false><<<g1 + ATT0_BLOCKS, 256, 0, stream>>>(node_idx, lg1, lg0, vbf,
                                                                 out_e, part, N, E, g1);
            k_att0_final<<<1, 256, 0, stream>>>(part, m2W1, m2W2, m2b2, n2g, n2b, c2, att0f);
            k_blk23<<<nb0 + nb1, 512, 0, stream>>>(vbf, 1, v_out, N, nb0, out_e, 0, out_e, E,
                m2W1p, m2W2p, m2b2, m3W1p, m3W2p, m3b2, n2g, n2b, n3g, n3b,
                c2 + 256, c3, att0f, ball, edge_orders);
        }
    } else {
        k_node<false><<<nnode, 256, 0, stream>>>(x, m1W1p, m1b1, m1W2p, m1b2, n1g, n1b,
                                                 kWp, kb, vWp, vb, q01, v_out, nullptr,
                                                 lg0, lg1, N);
        k_att0_partial<false><<<ATT0_BLOCKS, 256, 0, stream>>>(lg0, v_out, nullptr, N, part);
        k_att0_final<<<1, 256, 0, stream>>>(part, m2W1, m2W2, m2b2, n2g, n2b, c2, att0f);
        k_att1e<<<E, 256, 0, stream>>>(node_idx, lg1, v_out, out_e);
        k_blk23<<<nb0 + nb1, 512, 0, stream>>>(v_out, 0, v_out, N, nb0, out_e, 0, out_e, E,
            m2W1p, m2W2p, m2b2, m3W1p, m3W2p, m3b2, n2g, n2b, n3g, n3b,
            c2 + 256, c3, att0f, ball, edge_orders);
    }
}

// Round 27
// 464.101 us; speedup vs baseline: 1.1593x; 1.1593x over previous
//
#include <hip/hip_runtime.h>
#include <math.h>

#define ATT0_BLOCKS 1024

typedef __attribute__((ext_vector_type(8))) short short8_t;
typedef __attribute__((ext_vector_type(4))) float f32x4;

// branch-free GELU: gelu(x) = 0.5x + 0.5x*erf(x/sqrt2), erf via A&S 7.1.26
__device__ __forceinline__ float gelu_f(float x) {
    float ax = fabsf(x) * 0.70710678118654752f;
    float t = __builtin_amdgcn_rcpf(fmaf(ax, 0.3275911f, 1.0f));
    float p = fmaf(t, 1.061405429f, -1.453152027f);
    p = fmaf(t, p, 1.421413741f);
    p = fmaf(t, p, -0.284496736f);
    p = fmaf(t, p, 0.254829592f);
    p = p * t;
    float e = __expf(-ax * ax);
    float erfv = 1.0f - p * e;          // erf(|x|/sqrt2) >= 0
    return fmaf(0.5f * copysignf(erfv, x), x, 0.5f * x);
}

__device__ __forceinline__ float pe_val(int pos, int j, int D) {
    int i2 = j & ~1;
    float freq = expf(-9.210340371976184f * (float)i2 / (float)D); // -ln(10000)
    float arg = (float)pos * freq;
    return (j & 1) ? cosf(arg) : sinf(arg);
}

__device__ __forceinline__ unsigned short f2bf(float f) {
    unsigned u = __float_as_uint(f);
    return (unsigned short)((u + 0x7fffu + ((u >> 16) & 1u)) >> 16);
}
__device__ __forceinline__ float bf2f(unsigned short u) {
    return __uint_as_float(((unsigned)u) << 16);
}

// swizzled bf16 LDS tile: rows of 256 bf16 (512 B), byte ^= (row&7)<<4
__device__ __forceinline__ void st_bf(unsigned short* X2, int row, int col, unsigned short v) {
    int byte = (row * 512 + col * 2) ^ ((row & 7) << 4);
    *(unsigned short*)((char*)X2 + byte) = v;
}
__device__ __forceinline__ short8_t ldA(const unsigned short* X2, int m, int ks, int l) {
    int byte = (m * 512 + ks * 64 + ((l >> 4) << 4)) ^ ((m & 7) << 4);
    return *(const short8_t*)((const char*)X2 + byte);
}

// ---------------------------------------------------------------------------
// K0: pack ALL eight fp32 weights into fragment-linear bf16 in one launch.
// ---------------------------------------------------------------------------
__global__ __launch_bounds__(256) void k_pack_all(
    const float* __restrict__ s_m1W1, const float* __restrict__ s_m1W2,
    const float* __restrict__ s_kW,   const float* __restrict__ s_vW,
    const float* __restrict__ s_m2W1, const float* __restrict__ s_m2W2,
    const float* __restrict__ s_m3W1, const float* __restrict__ s_m3W2,
    unsigned short* __restrict__ pk)
{
    int b = blockIdx.x, tid = threadIdx.x;
    const float* src; int CT, ld, base; size_t dstOff;
    if (b < 256)       { src = s_m1W1; CT = 16; ld = 256; base = 0;    dstOff = 0; }
    else if (b < 512)  { src = s_m1W2; CT = 16; ld = 256; base = 256;  dstOff = 65536; }
    else if (b < 1024) { src = s_kW;   CT = 32; ld = 512; base = 512;  dstOff = 131072; }
    else if (b < 1280) { src = s_vW;   CT = 16; ld = 256; base = 1024; dstOff = 262144; }
    else if (b < 1536) { src = s_m2W1; CT = 16; ld = 256; base = 1280; dstOff = 327680; }
    else if (b < 1792) { src = s_m2W2; CT = 16; ld = 256; base = 1536; dstOff = 393216; }
    else if (b < 2048) { src = s_m3W1; CT = 16; ld = 256; base = 1792; dstOff = 458752; }
    else               { src = s_m3W2; CT = 16; ld = 256; base = 2048; dstOff = 524288; }
    int idx = (b - base) * 256 + tid;
    if (idx >= 4096 * CT) return;
    int i = idx & 7, l = (idx >> 3) & 63, fc = idx >> 9;
    int c = fc % CT, ks = fc / CT;
    int k = ks * 32 + ((l >> 4) << 3) + i;
    int col = c * 16 + (l & 15);
    pk[dstOff + idx] = f2bf(src[(size_t)k * ld + col]);
}

// ---------------------------------------------------------------------------
// MFMA stage, 2 row-tiles (32 rows) x NT col-tiles, setprio around MFMA loop
// ---------------------------------------------------------------------------
template <int NT>
__device__ __forceinline__ void mm_frag(const unsigned short* X2,
                                        const unsigned short* __restrict__ Wp,
                                        int CT, int ct0, int l, f32x4 acc[2][NT])
{
    #pragma unroll
    for (int rt = 0; rt < 2; ++rt)
        #pragma unroll
        for (int t = 0; t < NT; ++t)
            acc[rt][t] = (f32x4){0.f, 0.f, 0.f, 0.f};
    __builtin_amdgcn_s_setprio(1);
    #pragma unroll
    for (int ks = 0; ks < 8; ++ks) {
        short8_t a0 = ldA(X2, (l & 15), ks, l);
        short8_t a1 = ldA(X2, 16 + (l & 15), ks, l);
        #pragma unroll
        for (int t = 0; t < NT; ++t) {
            short8_t b = *(const short8_t*)(Wp + (size_t)((ks * CT + ct0 + t) * 64 + l) * 8);
            acc[0][t] = __builtin_amdgcn_mfma_f32_16x16x32_bf16(a0, b, acc[0][t], 0, 0, 0);
            acc[1][t] = __builtin_amdgcn_mfma_f32_16x16x32_bf16(a1, b, acc[1][t], 0, 0, 0);
        }
    }
    __builtin_amdgcn_s_setprio(0);
}

// ---------------------------------------------------------------------------
// Barrier-free LN over bf16 [32][272] with 256 threads: 8 lanes/row
// ---------------------------------------------------------------------------
__device__ __forceinline__ void ln32h_nb256(const unsigned short* Ah, unsigned short* X2,
                                            const float* __restrict__ g,
                                            const float* __restrict__ bvec, int tid)
{
    int l = tid & 7, row = tid >> 3;      // 32 rows x 8 lanes
    float s = 0.f, q = 0.f;
    #pragma unroll
    for (int i = 0; i < 32; ++i) {
        float v = bf2f(Ah[row * 272 + l + i * 8]); s += v; q += v * v;
    }
    #pragma unroll
    for (int off = 1; off < 8; off <<= 1) {
        s += __shfl_xor(s, off); q += __shfl_xor(q, off);
    }
    float mean = s * (1.f / 256.f);
    float rstd = rsqrtf(q * (1.f / 256.f) - mean * mean + 1e-5f);
    #pragma unroll
    for (int i = 0; i < 32; ++i) {
        int col = l + i * 8;
        float v = (bf2f(Ah[row * 272 + col]) - mean) * rstd * g[col] + bvec[col];
        st_bf(X2, row, col, f2bf(v));
    }
}

// ---------------------------------------------------------------------------
// Barrier-free LN over bf16 [32][272] with 512 threads: 16 lanes/row.
// Row-slice cached in registers: single LDS read pass.
// ---------------------------------------------------------------------------
__device__ __forceinline__ void ln32h_nb512(const unsigned short* Ah, unsigned short* X2,
                                            const float* __restrict__ g,
                                            const float* __restrict__ bvec, int tid)
{
    int l = tid & 15, row = tid >> 4;     // 32 rows x 16 lanes
    float lv[16];
    float s = 0.f, q = 0.f;
    #pragma unroll
    for (int i = 0; i < 16; ++i) {
        float v = bf2f(Ah[row * 272 + l + i * 16]);
        lv[i] = v;
        s += v; q += v * v;
    }
    #pragma unroll
    for (int off = 1; off < 16; off <<= 1) {
        s += __shfl_xor(s, off); q += __shfl_xor(q, off);
    }
    float mean = s * (1.f / 256.f);
    float rstd = rsqrtf(q * (1.f / 256.f) - mean * mean + 1e-5f);
    #pragma unroll
    for (int i = 0; i < 16; ++i) {
        int col = l + i * 16;
        float v = (lv[i] - mean) * rstd * g[col] + bvec[col];
        st_bf(X2, row, col, f2bf(v));
    }
}

// ---------------------------------------------------------------------------
// K1: tiny setup — q rows, bias rows, c2/c3 constant vectors
// ---------------------------------------------------------------------------
__global__ __launch_bounds__(256) void k_small(
    const float* __restrict__ qW1, const float* __restrict__ qb1,
    const float* __restrict__ qW2, const float* __restrict__ qb2,
    const float* __restrict__ bW1, const float* __restrict__ bb1,
    const float* __restrict__ bW2, const float* __restrict__ bb2,
    const float* __restrict__ m2W1, const float* __restrict__ m2b1,
    const float* __restrict__ m3W1, const float* __restrict__ m3b1,
    float* __restrict__ q01, float* __restrict__ ball,
    float* __restrict__ c2, float* __restrict__ c3)
{
    __shared__ float pe[256];
    __shared__ float h[256];
    int b = blockIdx.x, tid = threadIdx.x;
    if (b < 11) {
        int pos = (b < 2) ? b : (b - 2);
        if (tid < 64) pe[tid] = pe_val(pos, tid, 64);
        __syncthreads();
        const float* W1 = (b < 2) ? qW1 : bW1;
        const float* b1 = (b < 2) ? qb1 : bb1;
        const float* W2 = (b < 2) ? qW2 : bW2;
        const float* b2 = (b < 2) ? qb2 : bb2;
        float acc = b1[tid];
        for (int d = 0; d < 64; ++d) acc += pe[d] * W1[d * 256 + tid];
        h[tid] = gelu_f(acc);
        __syncthreads();
        float acc2 = b2[tid];
        for (int d = 0; d < 256; ++d) acc2 += h[d] * W2[d * 256 + tid];
        if (b < 2) q01[b * 256 + tid] = acc2;
        else ball[(b - 2) * 256 + tid] = acc2;
    } else {
        int pos; const float* W1; const float* b1; float* dst;
        if (b < 13) { pos = b - 11; W1 = m2W1; b1 = m2b1; dst = c2 + pos * 256; }
        else        { pos = b - 13; W1 = m3W1; b1 = m3b1; dst = c3 + pos * 256; }
        pe[tid] = pe_val(pos, tid, 256);
        __syncthreads();
        float acc = b1[tid];
        for (int d = 0; d < 256; ++d) acc += pe[d] * W1[(256 + d) * 256 + tid];
        dst[tid] = acc;
    }
}

// ---------------------------------------------------------------------------
// K2 (32-row, bf16 Ah + X2 dbuf, 4 barriers): x1 = x + mlp1(ln(x));
// v -> vbf (VB) or fp32; logits from kW accumulators
// ---------------------------------------------------------------------------
template <bool VB>
__global__ __launch_bounds__(256) void k_node(
    const float* __restrict__ x,
    const unsigned short* __restrict__ m1W1p, const float* __restrict__ m1b1,
    const unsigned short* __restrict__ m1W2p, const float* __restrict__ m1b2,
    const float* __restrict__ n1g, const float* __restrict__ n1b,
    const unsigned short* __restrict__ kWp, const float* __restrict__ kb,
    const unsigned short* __restrict__ vWp, const float* __restrict__ vb,
    const float* __restrict__ q01,
    float* __restrict__ v_out, unsigned short* __restrict__ vbf,
    float* __restrict__ lg0, float* __restrict__ lg1, int N)
{
    __shared__ __align__(16) unsigned short Ah[32 * 272];    // 17408 B
    __shared__ __align__(16) unsigned short X2a[32 * 256];   // 16384 B
    __shared__ __align__(16) unsigned short X2b[32 * 256];   // 16384 B

    int tid = threadIdx.x;
    int l = tid & 63, wid = tid >> 6, l15 = l & 15;
    int row0 = blockIdx.x * 32;

    {
        #pragma unroll
        for (int it = 0; it < 8; ++it) {
            int slot = it * 256 + tid;          // 2048 slots x 4 floats
            int row = slot >> 6, c0 = (slot & 63) * 4;
            int n = row0 + row;
            float4 f = (n < N) ? *(const float4*)(x + (size_t)n * 256 + c0)
                               : (float4){0.f, 0.f, 0.f, 0.f};
            ushort4 hv = {f2bf(f.x), f2bf(f.y), f2bf(f.z), f2bf(f.w)};
            *(ushort4*)&Ah[row * 272 + c0] = hv;
        }
    }
    __syncthreads();                               // B1: Ah visible
    ln32h_nb256(Ah, X2a, n1g, n1b, tid);
    __syncthreads();                               // B2: X2a (LN) visible

    f32x4 acc[2][4];
    // mlp1 stage 1: read X2a, write h -> X2b
    mm_frag<4>(X2a, m1W1p, 16, wid * 4, l, acc);
    #pragma unroll
    for (int rt = 0; rt < 2; ++rt)
        #pragma unroll
        for (int t = 0; t < 4; ++t) {
            int col = (wid * 4 + t) * 16 + l15;
            float bb = m1b1[col];
            #pragma unroll
            for (int r = 0; r < 4; ++r) {
                int row = rt * 16 + ((l >> 4) << 2) + r;
                st_bf(X2b, row, col, f2bf(gelu_f(acc[rt][t][r] + bb)));
            }
        }
    __syncthreads();                               // B3: h (X2b) visible
    // mlp1 stage 2: read X2b, x1 = Ah + acc + b -> X2a
    mm_frag<4>(X2b, m1W2p, 16, wid * 4, l, acc);
    #pragma unroll
    for (int rt = 0; rt < 2; ++rt)
        #pragma unroll
        for (int t = 0; t < 4; ++t) {
            int col = (wid * 4 + t) * 16 + l15;
            float bb = m1b2[col];
            #pragma unroll
            for (int r = 0; r < 4; ++r) {
                int row = rt * 16 + ((l >> 4) << 2) + r;
                float nv = bf2f(Ah[row * 272 + col]) + acc[rt][t][r] + bb;
                st_bf(X2a, row, col, f2bf(nv));
            }
        }
    __syncthreads();                               // B4: x1 (X2a) visible

    {
        f32x4 acck[2][8];
        mm_frag<8>(X2a, kWp, 32, wid * 8, l, acck);
        int which = wid >> 1;
        int h0 = (wid & 1) * 4;
        float lp[2][4][4];
        #pragma unroll
        for (int rt = 0; rt < 2; ++rt)
            #pragma unroll
            for (int r = 0; r < 4; ++r)
                #pragma unroll
                for (int hl = 0; hl < 4; ++hl) lp[rt][r][hl] = 0.f;
        #pragma unroll
        for (int t = 0; t < 8; ++t) {
            int d = ((t & 1) << 4) | l15;
            int h = h0 + (t >> 1);
            int col = (which * 16 + (wid & 1) * 8 + t) * 16 + l15;
            float qv = q01[which * 256 + h * 32 + d];
            float kbv = kb[col];
            #pragma unroll
            for (int rt = 0; rt < 2; ++rt)
                #pragma unroll
                for (int r = 0; r < 4; ++r)
                    lp[rt][r][t >> 1] += qv * (acck[rt][t][r] + kbv);
        }
        #pragma unroll
        for (int off = 1; off < 16; off <<= 1)
            #pragma unroll
            for (int rt = 0; rt < 2; ++rt)
                #pragma unroll
                for (int r = 0; r < 4; ++r)
                    #pragma unroll
                    for (int hl = 0; hl < 4; ++hl)
                        lp[rt][r][hl] += __shfl_xor(lp[rt][r][hl], off);
        if (l15 == 0) {
            float* dst = which ? lg1 : lg0;
            #pragma unroll
            for (int rt = 0; rt < 2; ++rt)
                #pragma unroll
                for (int r = 0; r < 4; ++r) {
                    int n = row0 + rt * 16 + ((l >> 4) << 2) + r;
                    if (n < N)
                        #pragma unroll
                        for (int hl = 0; hl < 4; ++hl)
                            dst[(size_t)n * 8 + h0 + hl] = lp[rt][r][hl] * 0.17677669529663687f;
                }
        }
    }
    mm_frag<4>(X2a, vWp, 16, wid * 4, l, acc);
    #pragma unroll
    for (int rt = 0; rt < 2; ++rt)
        #pragma unroll
        for (int t = 0; t < 4; ++t) {
            int col = (wid * 4 + t) * 16 + l15;
            float bb = vb[col];
            #pragma unroll
            for (int r = 0; r < 4; ++r) {
                int n = row0 + rt * 16 + ((l >> 4) << 2) + r;
                if (n < N) {
                    float val = acc[rt][t][r] + bb;
                    if (VB) vbf[(size_t)n * 256 + col] = f2bf(val);
                    else    v_out[(size_t)n * 256 + col] = val;
                }
            }
        }
}

// ---------------------------------------------------------------------------
// K3 (merged): blocks [0,g1) = att1e gather; [g1,g1+ATT0_BLOCKS) = att0 partials
// ---------------------------------------------------------------------------
template <bool OBF>
__global__ __launch_bounds__(256) void k_gath0(
    const int* __restrict__ node_idx, const float* __restrict__ lg1,
    const float* __restrict__ lg0, const unsigned short* __restrict__ vbf,
    void* __restrict__ outp, float* __restrict__ part, int N, int E, int g1)
{
    __shared__ int nidS[32];
    int tid = threadIdx.x;
    if ((int)blockIdx.x < g1) {
        int wid = tid >> 6, l = tid & 63;
        int e = blockIdx.x * 4 + wid;
        bool alive = e < E;
        if (l < 8) nidS[wid * 8 + l] = alive ? node_idx[(size_t)e * 8 + l] : 0;
        __syncthreads();
        float lgv = lg1[(size_t)nidS[wid * 8 + (l >> 3)] * 8 + (l & 7)];
        float m = lgv;
        m = fmaxf(m, __shfl_xor(m, 8));
        m = fmaxf(m, __shfl_xor(m, 16));
        m = fmaxf(m, __shfl_xor(m, 32));
        float w = __expf(lgv - m);
        float den = w;
        den += __shfl_xor(den, 8);
        den += __shfl_xor(den, 16);
        den += __shfl_xor(den, 32);
        float wn = w / den;
        int c0 = l * 4, myh = l >> 3;
        float a0 = 0.f, a1 = 0.f, a2 = 0.f, a3 = 0.f;
        #pragma unroll
        for (int i = 0; i < 8; ++i) {
            float ws = __shfl(wn, i * 8 + myh);
            int ni = nidS[wid * 8 + i];
            ushort4 pv = *(const ushort4*)(vbf + (size_t)ni * 256 + c0);
            a0 = fmaf(ws, bf2f(pv.x), a0);
            a1 = fmaf(ws, bf2f(pv.y), a1);
            a2 = fmaf(ws, bf2f(pv.z), a2);
            a3 = fmaf(ws, bf2f(pv.w), a3);
        }
        if (alive) {
            if (OBF) {
                ushort4 o = {f2bf(a0), f2bf(a1), f2bf(a2), f2bf(a3)};
                *(ushort4*)((unsigned short*)outp + (size_t)e * 256 + c0) = o;
            } else {
                float4 o = {a0, a1, a2, a3};
                *(float4*)((float*)outp + (size_t)e * 256 + c0) = o;
            }
        }
    } else {
        int b = (int)blockIdx.x - g1;
        int chunk = (N + ATT0_BLOCKS - 1) / ATT0_BLOCKS;
        int n0 = b * chunk, n1 = min(N, n0 + chunk);
        int h = tid >> 5;
        float acc = 0.f, dacc = 0.f;
        for (int n = n0; n < n1; ++n) {
            float e = __expf(lg0[(size_t)n * 8 + h]);
            float vv = bf2f(vbf[(size_t)n * 256 + tid]);
            acc += e * vv;
            if ((tid & 31) == 0) dacc += e;
        }
        part[b * 264 + tid] = acc;
        if ((tid & 31) == 0) part[b * 264 + 256 + h] = dacc;
    }
}

// fp32 fallback variants
template <bool BF>
__global__ __launch_bounds__(256) void k_att0_partial(
    const float* __restrict__ lg0, const float* __restrict__ v,
    const unsigned short* __restrict__ vbf, int N, float* __restrict__ part)
{
    int tid = threadIdx.x, b = blockIdx.x;
    int chunk = (N + ATT0_BLOCKS - 1) / ATT0_BLOCKS;
    int n0 = b * chunk, n1 = min(N, n0 + chunk);
    int h = tid >> 5;
    float acc = 0.f, dacc = 0.f;
    for (int n = n0; n < n1; ++n) {
        float e = __expf(lg0[(size_t)n * 8 + h]);
        float vv = BF ? bf2f(vbf[(size_t)n * 256 + tid]) : v[(size_t)n * 256 + tid];
        acc += e * vv;
        if ((tid & 31) == 0) dacc += e;
    }
    part[b * 264 + tid] = acc;
    if ((tid & 31) == 0) part[b * 264 + 256 + h] = dacc;
}

__global__ __launch_bounds__(256) void k_att0_final(
    const float* __restrict__ part,
    const float* __restrict__ m2W1, const float* __restrict__ m2W2,
    const float* __restrict__ m2b2,
    const float* __restrict__ n2g, const float* __restrict__ n2b,
    const float* __restrict__ c2, float* __restrict__ att0f)
{
    __shared__ float L[256], H[256], red[16], dsh[8];
    int tid = threadIdx.x;
    float s = 0.f;
    for (int b = 0; b < ATT0_BLOCKS; ++b) s += part[b * 264 + tid];
    if (tid < 8) {
        float d = 0.f;
        for (int b = 0; b < ATT0_BLOCKS; ++b) d += part[b * 264 + 256 + tid];
        dsh[tid] = d;
    }
    __syncthreads();
    float a = s / dsh[tid >> 5];
    float ss = a, sq = a * a;
    for (int off = 32; off; off >>= 1) { ss += __shfl_down(ss, off); sq += __shfl_down(sq, off); }
    int lane = tid & 63, wid = tid >> 6;
    if (lane == 0) { red[wid] = ss; red[4 + wid] = sq; }
    __syncthreads();
    if (tid == 0) {
        float S1 = red[0] + red[1] + red[2] + red[3];
        float S2 = red[4] + red[5] + red[6] + red[7];
        float mean = S1 / 256.f, var = S2 / 256.f - mean * mean;
        red[8] = mean; red[9] = rsqrtf(var + 1e-5f);
    }
    __syncthreads();
    L[tid] = (a - red[8]) * red[9] * n2g[tid] + n2b[tid];
    __syncthreads();
    float acc = c2[tid];
    for (int d = 0; d < 256; ++d) acc += L[d] * m2W1[d * 256 + tid];
    H[tid] = gelu_f(acc);
    __syncthreads();
    float acc2 = m2b2[tid];
    for (int d = 0; d < 256; ++d) acc2 += H[d] * m2W2[d * 256 + tid];
    att0f[tid] = a + acc2;
}

// fp32 fallback (block-per-edge)
__global__ __launch_bounds__(256) void k_att1e(
    const int* __restrict__ node_idx, const float* __restrict__ lg1,
    const float* __restrict__ v, float* __restrict__ oute)
{
    __shared__ int nid[8];
    __shared__ float lgS[64];
    int e = blockIdx.x, tid = threadIdx.x;
    if (tid < 8) nid[tid] = node_idx[e * 8 + tid];
    __syncthreads();
    if (tid < 64) { int i = tid >> 3, h = tid & 7; lgS[i * 8 + h] = lg1[(size_t)nid[i] * 8 + h]; }
    __syncthreads();
    int h = tid >> 5;
    float m = -1e30f;
    #pragma unroll
    for (int i = 0; i < 8; ++i) m = fmaxf(m, lgS[i * 8 + h]);
    float w[8], den = 0.f;
    #pragma unroll
    for (int i = 0; i < 8; ++i) { w[i] = __expf(lgS[i * 8 + h] - m); den += w[i]; }
    float acc = 0.f;
    #pragma unroll
    for (int i = 0; i < 8; ++i) acc += w[i] * v[(size_t)nid[i] * 256 + tid];
    oute[(size_t)e * 256 + tid] = acc / den;
}

// ---------------------------------------------------------------------------
// K5 (512 threads, 32 rows, acc[2][2] col-pair waves — no duplicate B-loads):
// blk2+att0+blk3+bias, 6 barriers per 32 rows. [0,nb0)=node; [nb0,..)=edge.
// ---------------------------------------------------------------------------
__global__ __launch_bounds__(512) void k_blk23(
    const void* __restrict__ in_v, int node_bf, float* __restrict__ out_v, int Mn, int nb0,
    const void* __restrict__ in_e, int edge_bf, float* __restrict__ out_e, int Me,
    const unsigned short* __restrict__ m2W1p, const unsigned short* __restrict__ m2W2p,
    const float* __restrict__ m2b2,
    const unsigned short* __restrict__ m3W1p, const unsigned short* __restrict__ m3W2p,
    const float* __restrict__ m3b2,
    const float* __restrict__ n2g, const float* __restrict__ n2b,
    const float* __restrict__ n3g, const float* __restrict__ n3b,
    const float* __restrict__ c2row, const float* __restrict__ c3tab,
    const float* __restrict__ att0f, const float* __restrict__ ball,
    const int* __restrict__ orders)
{
    __shared__ __align__(16) unsigned short Ah[32 * 272];    // 17408 B
    __shared__ __align__(16) unsigned short X2a[32 * 256];   // 16384 B
    __shared__ __align__(16) unsigned short X2b[32 * 256];   // 16384 B
    __shared__ int ords[32];

    int tid = threadIdx.x;
    int l = tid & 63, wid = tid >> 6, l15 = l & 15, gq = l >> 4;
    bool edge = (int)blockIdx.x >= nb0;
    int row0 = (edge ? (int)blockIdx.x - nb0 : (int)blockIdx.x) * 32;
    int M = edge ? Me : Mn;
    float* outp = edge ? out_e : out_v;
    int inbf = edge ? edge_bf : node_bf;
    const void* inp = edge ? in_e : in_v;

    if (inbf) {
        const unsigned short* inH = (const unsigned short*)inp;
        #pragma unroll
        for (int it = 0; it < 4; ++it) {
            int slot = it * 512 + tid;          // 2048 slots x 4 bf16
            int row = slot >> 6, c0 = (slot & 63) * 4;
            int n = row0 + row;
            ushort4 hv = (n < M) ? *(const ushort4*)(inH + (size_t)n * 256 + c0)
                                 : (ushort4){0, 0, 0, 0};
            *(ushort4*)&Ah[row * 272 + c0] = hv;
        }
    } else {
        const float* inF = (const float*)inp;
        #pragma unroll
        for (int it = 0; it < 4; ++it) {
            int slot = it * 512 + tid;
            int row = slot >> 6, c0 = (slot & 63) * 4;
            int n = row0 + row;
            float4 f = (n < M) ? *(const float4*)(inF + (size_t)n * 256 + c0)
                               : (float4){0.f, 0.f, 0.f, 0.f};
            ushort4 hv = {f2bf(f.x), f2bf(f.y), f2bf(f.z), f2bf(f.w)};
            *(ushort4*)&Ah[row * 272 + c0] = hv;
        }
    }
    if (tid < 32) {
        int n = row0 + tid;
        ords[tid] = (edge && n < M) ? orders[n] : 1;
    }
    __syncthreads();                               // B1: Ah + ords visible

    f32x4 acc[2][2];
    // ---- blk2 ----
    ln32h_nb512(Ah, X2a, n2g, n2b, tid);
    __syncthreads();                               // B2: X2a (LN) visible
    mm_frag<2>(X2a, m2W1p, 16, wid * 2, l, acc);
    #pragma unroll
    for (int rt = 0; rt < 2; ++rt)
        #pragma unroll
        for (int t = 0; t < 2; ++t) {
            int col = (wid * 2 + t) * 16 + l15;
            float bb = c2row[col];
            #pragma unroll
            for (int r = 0; r < 4; ++r)
                st_bf(X2b, rt * 16 + gq * 4 + r, col, f2bf(gelu_f(acc[rt][t][r] + bb)));
        }
    __syncthreads();                               // B3: h (X2b) visible
    mm_frag<2>(X2b, m2W2p, 16, wid * 2, l, acc);
    #pragma unroll
    for (int rt = 0; rt < 2; ++rt)
        #pragma unroll
        for (int t = 0; t < 2; ++t) {
            int col = (wid * 2 + t) * 16 + l15;
            float bb = m2b2[col] + att0f[col];
            #pragma unroll
            for (int r = 0; r < 4; ++r) {
                int row = rt * 16 + gq * 4 + r;
                float nv = bf2f(Ah[row * 272 + col]) + acc[rt][t][r] + bb;
                Ah[row * 272 + col] = f2bf(nv);
            }
        }
    __syncthreads();                               // B4: Ah updated
    // ---- blk3 ----
    ln32h_nb512(Ah, X2a, n3g, n3b, tid);
    __syncthreads();                               // B5: X2a visible
    mm_frag<2>(X2a, m3W1p, 16, wid * 2, l, acc);
    #pragma unroll
    for (int rt = 0; rt < 2; ++rt)
        #pragma unroll
        for (int t = 0; t < 2; ++t) {
            int col = (wid * 2 + t) * 16 + l15;
            #pragma unroll
            for (int r = 0; r < 4; ++r) {
                int row = rt * 16 + gq * 4 + r;
                float bb = c3tab[ords[row] * 256 + col];
                st_bf(X2b, row, col, f2bf(gelu_f(acc[rt][t][r] + bb)));
            }
        }
    __syncthreads();                               // B6: h (X2b) visible
    mm_frag<2>(X2b, m3W2p, 16, wid * 2, l, acc);
    #pragma unroll
    for (int rt = 0; rt < 2; ++rt)
        #pragma unroll
        for (int t = 0; t < 2; ++t) {
            int col = (wid * 2 + t) * 16 + l15;
            float bb = m3b2[col];
            #pragma unroll
            for (int r = 0; r < 4; ++r) {
                int row = rt * 16 + gq * 4 + r;
                int n = row0 + row;
                if (n < M)
                    outp[(size_t)n * 256 + col] =
                        bf2f(Ah[row * 272 + col]) + acc[rt][t][r] + bb
                        + ball[ords[row] * 256 + col];
            }
        }
}

extern "C" void kernel_launch(void* const* d_in, const int* in_sizes, int n_in,
                              void* d_out, int out_size, void* d_ws, size_t ws_size,
                              hipStream_t stream)
{
    const float* x          = (const float*)d_in[0];
    const int*   node_idx   = (const int*)d_in[1];
    const int*   edge_orders= (const int*)d_in[3];
    const float* qW1 = (const float*)d_in[4];
    const float* qb1 = (const float*)d_in[5];
    const float* qW2 = (const float*)d_in[6];
    const float* qb2 = (const float*)d_in[7];
    const float* kW  = (const float*)d_in[8];
    const float* kb  = (const float*)d_in[9];
    const float* vW  = (const float*)d_in[10];
    const float* vb  = (const float*)d_in[11];
    const float* m1W1= (const float*)d_in[12];
    const float* m1b1= (const float*)d_in[13];
    const float* m1W2= (const float*)d_in[14];
    const float* m1b2= (const float*)d_in[15];
    const float* m2W1= (const float*)d_in[16];
    const float* m2b1= (const float*)d_in[17];
    const float* m2W2= (const float*)d_in[18];
    const float* m2b2= (const float*)d_in[19];
    const float* m3W1= (const float*)d_in[20];
    const float* m3b1= (const float*)d_in[21];
    const float* m3W2= (const float*)d_in[22];
    const float* m3b2= (const float*)d_in[23];
    const float* n1g = (const float*)d_in[24];
    const float* n1b = (const float*)d_in[25];
    const float* n2g = (const float*)d_in[26];
    const float* n2b = (const float*)d_in[27];
    const float* n3g = (const float*)d_in[28];
    const float* n3b = (const float*)d_in[29];
    const float* bW1 = (const float*)d_in[30];
    const float* bb1 = (const float*)d_in[31];
    const float* bW2 = (const float*)d_in[32];
    const float* bb2 = (const float*)d_in[33];

    int N = in_sizes[0] / 256;
    int E = in_sizes[3];

    float* ws    = (float*)d_ws;
    float* q01   = ws;               // 512
    float* ball  = ws + 512;         // 9*256
    float* c2    = ws + 2816;        // 2*256
    float* c3    = ws + 3328;        // 9*256
    float* att0f = ws + 5632;        // 256
    float* part  = ws + 5888;        // 1024*264 -> ends 276224
    float* lg0   = ws + 276224;      // N*8
    float* lg1   = lg0 + (size_t)N * 8;            // ends 276224 + 2*N*8
    unsigned short* pk = (unsigned short*)(ws + 1076224);
    unsigned short* m1W1p = pk;
    unsigned short* m1W2p = pk + 65536;
    unsigned short* kWp   = pk + 131072;
    unsigned short* vWp   = pk + 262144;
    unsigned short* m2W1p = pk + 327680;
    unsigned short* m2W2p = pk + 393216;
    unsigned short* m3W1p = pk + 458752;
    unsigned short* m3W2p = pk + 524288;   // pk ends at float offset 1371136
    unsigned short* vbf = (unsigned short*)(ws + 1371136);
    unsigned short* aeb = vbf + (size_t)N * 256;
    size_t need1 = 1371136ull * 4 + (size_t)N * 256 * 2;
    size_t need2 = need1 + (size_t)E * 256 * 2;
    bool use_bf  = (ws_size >= need1);
    bool use_ebf = (ws_size >= need2);

    float* v_out = (float*)d_out;                       // [N,256]: x_v (fallback: v then x_v)
    float* out_e = (float*)d_out + (size_t)N * 256;     // [E,256]: att1_e, then x_e

    k_pack_all<<<2304, 256, 0, stream>>>(m1W1, m1W2, kW, vW, m2W1, m2W2, m3W1, m3W2, pk);
    k_small<<<22, 256, 0, stream>>>(qW1, qb1, qW2, qb2, bW1, bb1, bW2, bb2,
                                    m2W1, m2b1, m3W1, m3b1, q01, ball, c2, c3);

    int nb0 = (N + 31) / 32, nb1 = (E + 31) / 32;
    int nnode = (N + 31) / 32;
    int g1 = (E + 3) / 4;
    if (use_bf) {
        k_node<true><<<nnode, 256, 0, stream>>>(x, m1W1p, m1b1, m1W2p, m1b2, n1g, n1b,
                                                kWp, kb, vWp, vb, q01, nullptr, vbf,
                                                lg0, lg1, N);
        if (use_ebf) {
            k_gath0<true><<<g1 + ATT0_BLOCKS, 256, 0, stream>>>(node_idx, lg1, lg0, vbf,
                                                                aeb, part, N, E, g1);
            k_att0_final<<<1, 256, 0, stream>>>(part, m2W1, m2W2, m2b2, n2g, n2b, c2, att0f);
            k_blk23<<<nb0 + nb1, 512, 0, stream>>>(vbf, 1, v_out, N, nb0, aeb, 1, out_e, E,
                m2W1p, m2W2p, m2b2, m3W1p, m3W2p, m3b2, n2g, n2b, n3g, n3b,
                c2 + 256, c3, att0f, ball, edge_orders);
        } else {
            k_gath0<false><<<g1 + ATT0_BLOCKS, 256, 0, stream>>>(node_idx, lg1, lg0, vbf,
                                                                 out_e, part, N, E, g1);
            k_att0_final<<<1, 256, 0, stream>>>(part, m2W1, m2W2, m2b2, n2g, n2b, c2, att0f);
            k_blk23<<<nb0 + nb1, 512, 0, stream>>>(vbf, 1, v_out, N, nb0, out_e, 0, out_e, E,
                m2W1p, m2W2p, m2b2, m3W1p, m3W2p, m3b2, n2g, n2b, n3g, n3b,
                c2 + 256, c3, att0f, ball, edge_orders);
        }
    } else {
        k_node<false><<<nnode, 256, 0, stream>>>(x, m1W1p, m1b1, m1W2p, m1b2, n1g, n1b,
                                                 kWp, kb, vWp, vb, q01, v_out, nullptr,
                                                 lg0, lg1, N);
        k_att0_partial<false><<<ATT0_BLOCKS, 256, 0, stream>>>(lg0, v_out, nullptr, N, part);
        k_att0_final<<<1, 256, 0, stream>>>(part, m2W1, m2W2, m2b2, n2g, n2b, c2, att0f);
        k_att1e<<<E, 256, 0, stream>>>(node_idx, lg1, v_out, out_e);
        k_blk23<<<nb0 + nb1, 512, 0, stream>>>(v_out, 0, v_out, N, nb0, out_e, 0, out_e, E,
            m2W1p, m2W2p, m2b2, m3W1p, m3W2p, m3b2, n2g, n2b, n3g, n3b,
            c2 + 256, c3, att0f, ball, edge_orders);
    }
}